// Round 5
// baseline (277.292 us; speedup 1.0000x reference)
//
#include <hip/hip_runtime.h>
#include <hip/hip_fp16.h>

#define BATCH 2
#define SEQ 2048
#define EMB 1024
#define NH 16
#define HDIM 64

typedef _Float16 h16;
typedef __attribute__((ext_vector_type(8))) _Float16 h8;
typedef __attribute__((ext_vector_type(4))) _Float16 h4;
typedef __attribute__((ext_vector_type(4))) float f32x4;

#define MFMA16(a, b, c) __builtin_amdgcn_mfma_f32_16x16x32_f16((a), (b), (c), 0, 0, 0)

// async global->LDS, 16B per lane. LDS dest is wave-uniform base + lane*16.
__device__ __forceinline__ void g2l16(const void* g, void* l) {
    __builtin_amdgcn_global_load_lds(
        (const __attribute__((address_space(1))) unsigned int*)g,
        (__attribute__((address_space(3))) unsigned int*)l, 16, 0, 0);
}

// ---------------------------------------------------------------------------
// x [B*S][E] f32 -> f16
__global__ __launch_bounds__(256) void k_cast_x(const float* __restrict__ x,
                                                h16* __restrict__ xh) {
    int i = (blockIdx.x * 256 + threadIdx.x) * 4;
    float4 v = *(const float4*)(x + i);
    h4 o = { (h16)v.x, (h16)v.y, (h16)v.z, (h16)v.w };
    *(h4*)(xh + i) = o;
}

// Wq/Wk/Wv [NH][EMB][HDIM] f32 -> wcat[(h*3+mat)*64+d][EMB] f16 (n-major, k-contig)
__global__ __launch_bounds__(256) void k_tr_qkv3(const float* __restrict__ wq,
                                                 const float* __restrict__ wk,
                                                 const float* __restrict__ wv,
                                                 h16* __restrict__ wcat) {
    int o = blockIdx.x * 256 + threadIdx.x;       // [0, 3M)
    int mat = o >> 20;
    int w = o & ((1 << 20) - 1);
    int e = w & 1023, d = (w >> 10) & 63, h = w >> 16;
    const float* src = (mat == 0) ? wq : (mat == 1) ? wk : wv;
    wcat[(((size_t)(h * 3 + mat) * 64 + d) << 10) | e] =
        (h16)src[((size_t)(h << 10) + e) * 64 + d];
}

// Wproj [PROJ_IN][EMB] f32 -> wpt [EMB_n][PROJ_IN_k] f16
__global__ __launch_bounds__(256) void k_tr_wp(const float* __restrict__ w,
                                               h16* __restrict__ wt) {
    int o = blockIdx.x * 256 + threadIdx.x;
    int k = o & 1023, n = o >> 10;
    wt[o] = (h16)w[((size_t)k << 10) | n];
}

// ---------------------------------------------------------------------------
// m97-structure QKV GEMM: M=4096, N=3072, K=1024. 128x128 tile, BK=32.
__global__ __launch_bounds__(256) void k_qkv(
    const h16* __restrict__ xh, const h16* __restrict__ wcat,
    h16* __restrict__ Q, h16* __restrict__ Kk, h16* __restrict__ Vt) {
    __shared__ h16 As[128 * 32];
    __shared__ h16 Bs[128 * 32];
    int tid = threadIdx.x;
    int wave = tid >> 6, lane = tid & 63;
    int lr = lane & 15, lg = lane >> 4;
    int wr = wave >> 1, wc = wave & 1;
    // bijective XCD swizzle: 768 = 8 * 96 -> same-mt blocks co-locate per XCD
    int swz = (blockIdx.x & 7) * 96 + (blockIdx.x >> 3);
    int nt = swz % 24, mt = swz / 24;

    const char* Ab = (const char*)xh + (size_t)mt * 128 * 2048;
    const char* Bb = (const char*)wcat + (size_t)nt * 128 * 2048;
    int srow = tid >> 2;                                   // 0..63
    int scolb = (((tid & 3) ^ (srow & 3))) * 16;           // swizzled source granule
    const char* As0 = Ab + (size_t)srow * 2048 + scolb;
    const char* Bs0 = Bb + (size_t)srow * 2048 + scolb;
    h16* AsW = As + wave * 512;                            // per-wave 1KB staging base
    h16* BsW = Bs + wave * 512;

    f32x4 acc[4][4];
#pragma unroll
    for (int m = 0; m < 4; m++)
#pragma unroll
        for (int n = 0; n < 4; n++) acc[m][n] = (f32x4){0.f, 0.f, 0.f, 0.f};

    for (int k0 = 0; k0 < 1024; k0 += 32) {
        size_t kb = (size_t)k0 * 2;
        g2l16(As0 + kb, AsW);
        g2l16(As0 + 64 * 2048 + kb, AsW + 2048);
        g2l16(Bs0 + kb, BsW);
        g2l16(Bs0 + 64 * 2048 + kb, BsW + 2048);
        __syncthreads();
        h8 a[4], b[4];
#pragma unroll
        for (int m = 0; m < 4; m++)
            a[m] = *(const h8*)&As[(wr * 64 + m * 16 + lr) * 32 + (lg ^ (lr & 3)) * 8];
#pragma unroll
        for (int n = 0; n < 4; n++)
            b[n] = *(const h8*)&Bs[(wc * 64 + n * 16 + lr) * 32 + (lg ^ (lr & 3)) * 8];
#pragma unroll
        for (int m = 0; m < 4; m++)
#pragma unroll
            for (int n = 0; n < 4; n++)
                acc[m][n] = MFMA16(a[m], b[n], acc[m][n]);
        __syncthreads();
    }

    int g = nt * 2 + wc;
    int mat = g % 3, hh = g / 3;
    int row0 = mt * 128 + wr * 64;
    if (mat == 2) {
#pragma unroll
        for (int m = 0; m < 4; m++)
#pragma unroll
            for (int n = 0; n < 4; n++) {
                int row = row0 + m * 16 + lg * 4;
                int b = row >> 11, s = row & 2047;
                int bh = b * 16 + hh;
                int d = n * 16 + lr;
                h4 o = { (h16)acc[m][n][0], (h16)acc[m][n][1],
                         (h16)acc[m][n][2], (h16)acc[m][n][3] };
                *(h4*)&Vt[((size_t)bh * 64 + d) * 2048 + s] = o;
            }
    } else {
        h16* dst = mat ? Kk : Q;
#pragma unroll
        for (int m = 0; m < 4; m++)
#pragma unroll
            for (int n = 0; n < 4; n++)
#pragma unroll
                for (int r = 0; r < 4; r++) {
                    int row = row0 + m * 16 + lg * 4 + r;
                    int bh = (row >> 11) * 16 + hh, s = row & 2047;
                    dst[((size_t)bh * 2048 + s) * 64 + n * 16 + lr] = (h16)acc[m][n][r];
                }
    }
}

// ---------------------------------------------------------------------------
// m97-structure out-projection: M=4096, N=1024, K=1024. 128x64 tile, BK=32.
__global__ __launch_bounds__(256) void k_proj(
    const h16* __restrict__ att, const h16* __restrict__ wpt,
    const float* __restrict__ bias, float* __restrict__ out) {
    __shared__ h16 As[128 * 32];
    __shared__ h16 Bs[64 * 32];
    int tid = threadIdx.x;
    int wave = tid >> 6, lane = tid & 63;
    int lr = lane & 15, lg = lane >> 4;
    int swz = (blockIdx.x & 7) * 64 + (blockIdx.x >> 3);   // 512 = 8*64 bijective
    int nt = swz & 15, mt = swz >> 4;

    const char* Ab = (const char*)att + (size_t)mt * 128 * 2048;
    const char* Bb = (const char*)wpt + (size_t)nt * 64 * 2048;
    int srow = tid >> 2;
    int scolb = (((tid & 3) ^ (srow & 3))) * 16;
    const char* As0 = Ab + (size_t)srow * 2048 + scolb;
    const char* Bs0 = Bb + (size_t)srow * 2048 + scolb;
    h16* AsW = As + wave * 512;
    h16* BsW = Bs + wave * 512;

    f32x4 acc[2][4];
#pragma unroll
    for (int m = 0; m < 2; m++)
#pragma unroll
        for (int n = 0; n < 4; n++) acc[m][n] = (f32x4){0.f, 0.f, 0.f, 0.f};

    for (int k0 = 0; k0 < 1024; k0 += 32) {
        size_t kb = (size_t)k0 * 2;
        g2l16(As0 + kb, AsW);
        g2l16(As0 + 64 * 2048 + kb, AsW + 2048);
        g2l16(Bs0 + kb, BsW);
        __syncthreads();
        h8 a[2], b[4];
#pragma unroll
        for (int m = 0; m < 2; m++)
            a[m] = *(const h8*)&As[(wave * 32 + m * 16 + lr) * 32 + (lg ^ (lr & 3)) * 8];
#pragma unroll
        for (int n = 0; n < 4; n++)
            b[n] = *(const h8*)&Bs[(n * 16 + lr) * 32 + (lg ^ (lr & 3)) * 8];
#pragma unroll
        for (int m = 0; m < 2; m++)
#pragma unroll
            for (int n = 0; n < 4; n++)
                acc[m][n] = MFMA16(a[m], b[n], acc[m][n]);
        __syncthreads();
    }

#pragma unroll
    for (int m = 0; m < 2; m++)
#pragma unroll
        for (int n = 0; n < 4; n++)
#pragma unroll
            for (int r = 0; r < 4; r++) {
                int row = mt * 128 + wave * 32 + m * 16 + lg * 4 + r;
                int col = nt * 64 + n * 16 + lr;
                out[(size_t)row * 1024 + col] = acc[m][n][r] + bias[col];
            }
}

// ---------------------------------------------------------------------------
// Transposed flash attention, 16-row q-chunks for 16 waves/CU occupancy.
// Grid: bh(32) x 32 blocks; wave w of block j -> chunk {j, 63-j, 64+j, 127-j}
// (exactly 66 tile-units per block). Q pre-scaled by 0.125*log2e once.
// S^T = mfma(K, Q): lane owns the k-column slice of one q-row (q = lane&15);
// softmax fully in-lane + 2 shfls; defer-max THR=8; no barriers.
__global__ __launch_bounds__(256, 4) void k_attn(
    const h16* __restrict__ Q, const h16* __restrict__ Kk,
    const h16* __restrict__ Vt, h16* __restrict__ att) {
    __shared__ h16 lp[4][16][72];   // per-wave P tile [q][k], stride 144B

    int j = blockIdx.x & 31;
    int bh = blockIdx.x >> 5;
    int b = bh >> 4, h = bh & 15;
    int wave = threadIdx.x >> 6, lane = threadIdx.x & 63;
    int lr = lane & 15, lg = lane >> 4;
    int c = (wave == 0) ? j : (wave == 1) ? 63 - j : (wave == 2) ? 64 + j : 127 - j;
    int q0 = c * 16;

    const h16* Qp = Q + (size_t)bh * SEQ * HDIM;
    const h16* Kp = Kk + (size_t)bh * SEQ * HDIM;
    const h16* Vp = Vt + (size_t)bh * HDIM * SEQ;

    // Q as B-operand (col=q, k-dim=d), pre-scaled into exp2 domain
    const h16 scq = (h16)0.18033688011112042f;   // 0.125 * log2(e)
    h8 scv = { scq, scq, scq, scq, scq, scq, scq, scq };
    h8 qb[2];
#pragma unroll
    for (int dc = 0; dc < 2; dc++) {
        qb[dc] = *(const h8*)(Qp + (size_t)(q0 + lr) * 64 + dc * 32 + lg * 8);
        qb[dc] *= scv;
    }

    float mx = 0.f, lsum = 0.f;
    f32x4 ot[4];   // O^T acc: row d = df*16+lg*4+r, col q = lr
#pragma unroll
    for (int df = 0; df < 4; df++) ot[df] = (f32x4){0.f, 0.f, 0.f, 0.f};

    int nkt = (q0 >> 6) + 1;
    for (int kt = 0; kt < nkt; ++kt) {
        int ks0 = kt << 6;
        // ---- S^T = K @ Q^T : rows=k (4 frags), col=q (1 frag)
        f32x4 st[4];
#pragma unroll
        for (int kf = 0; kf < 4; kf++) st[kf] = (f32x4){0.f, 0.f, 0.f, 0.f};
#pragma unroll
        for (int dc = 0; dc < 2; dc++) {
            h8 ka[4];
#pragma unroll
            for (int kf = 0; kf < 4; kf++)
                ka[kf] = *(const h8*)(Kp + (size_t)(ks0 + kf * 16 + lr) * 64 + dc * 32 + lg * 8);
#pragma unroll
            for (int kf = 0; kf < 4; kf++)
                st[kf] = MFMA16(ka[kf], qb[dc], st[kf]);
        }
        // ---- prefetch V frags (fly during softmax VALU)
        h8 va[2][4];
#pragma unroll
        for (int kc = 0; kc < 2; kc++)
#pragma unroll
            for (int df = 0; df < 4; df++)
                va[kc][df] = *(const h8*)(Vp + (size_t)(df * 16 + lr) * 2048 + ks0 + kc * 32 + lg * 8);

        // ---- causal mask (boundary tile only; wave-uniform branch)
        if (ks0 + 64 > q0) {
            int qg = q0 + lr;
#pragma unroll
            for (int kf = 0; kf < 4; kf++)
#pragma unroll
                for (int r = 0; r < 4; r++) {
                    int kg = ks0 + kf * 16 + lg * 4 + r;
                    if (kg > qg) st[kf][r] = -1e30f;
                }
        }
        // ---- per-q tile max: 15 in-lane fmax + 2 shfls
        float tm = st[0][0];
#pragma unroll
        for (int kf = 0; kf < 4; kf++)
#pragma unroll
            for (int r = 0; r < 4; r++) tm = fmaxf(tm, st[kf][r]);
        tm = fmaxf(tm, __shfl_xor(tm, 16));
        tm = fmaxf(tm, __shfl_xor(tm, 32));
        // ---- defer-max: rescale only if tile max grew past THR=8
        if (__any(tm > mx + 8.f)) {
            float mn = fmaxf(mx, tm);
            float corr = exp2f(mx - mn);
            lsum *= corr;
#pragma unroll
            for (int df = 0; df < 4; df++) ot[df] *= corr;
            mx = mn;
        }
        // ---- P = exp2(st - m), pack 4 consecutive k -> b64 LDS write
        float ts = 0.f;
#pragma unroll
        for (int kf = 0; kf < 4; kf++) {
            float p0 = exp2f(st[kf][0] - mx);
            float p1 = exp2f(st[kf][1] - mx);
            float p2 = exp2f(st[kf][2] - mx);
            float p3 = exp2f(st[kf][3] - mx);
            ts += (p0 + p1) + (p2 + p3);
            h4 ph = { (h16)p0, (h16)p1, (h16)p2, (h16)p3 };
            *(h4*)&lp[wave][lr][kf * 16 + lg * 4] = ph;
        }
        ts += __shfl_xor(ts, 16);
        ts += __shfl_xor(ts, 32);
        lsum += ts;
        // ---- O^T += V^T @ P^T
#pragma unroll
        for (int kc = 0; kc < 2; kc++) {
            h8 pb = *(const h8*)&lp[wave][lr][kc * 32 + lg * 8];
#pragma unroll
            for (int df = 0; df < 4; df++)
                ot[df] = MFMA16(va[kc][df], pb, ot[df]);
        }
    }
    // ---- epilogue: O^T/l -> att[b*S+q][h*64+d], 4 consecutive d packed
    float rl = 1.f / lsum;
    int q = q0 + lr;
#pragma unroll
    for (int df = 0; df < 4; df++) {
        h4 o = { (h16)(ot[df][0] * rl), (h16)(ot[df][1] * rl),
                 (h16)(ot[df][2] * rl), (h16)(ot[df][3] * rl) };
        *(h4*)&att[((size_t)(b * SEQ + q)) * 1024 + h * 64 + df * 16 + lg * 4] = o;
    }
}

// ---------------------------------------------------------------------------
extern "C" void kernel_launch(void* const* d_in, const int* in_sizes, int n_in,
                              void* d_out, int out_size, void* d_ws, size_t ws_size,
                              hipStream_t stream) {
    const float* x = (const float*)d_in[0];
    const float* Wq = (const float*)d_in[1];
    const float* Wk = (const float*)d_in[2];
    const float* Wv = (const float*)d_in[3];
    const float* Wp = (const float*)d_in[4];
    const float* bp = (const float*)d_in[5];
    float* out = (float*)d_out;

    char* p = (char*)d_ws;
    h16* xh = (h16*)p;   p += (size_t)BATCH * SEQ * EMB * 2;
    h16* wcat = (h16*)p; p += (size_t)NH * 3 * HDIM * EMB * 2;
    h16* wpt = (h16*)p;  p += (size_t)EMB * EMB * 2;
    h16* Qb = (h16*)p;   p += (size_t)BATCH * NH * SEQ * HDIM * 2;
    h16* Kb = (h16*)p;   p += (size_t)BATCH * NH * SEQ * HDIM * 2;
    h16* Vb = (h16*)p;   p += (size_t)BATCH * NH * SEQ * HDIM * 2;
    h16* attb = (h16*)p;

    k_cast_x<<<(BATCH * SEQ * EMB) / 4 / 256, 256, 0, stream>>>(x, xh);
    k_tr_qkv3<<<3 * NH * EMB * HDIM / 256, 256, 0, stream>>>(Wq, Wk, Wv, wcat);
    k_tr_wp<<<EMB * EMB / 256, 256, 0, stream>>>(Wp, wpt);
    k_qkv<<<32 * 24, 256, 0, stream>>>(xh, wcat, Qb, Kb, Vb);
    k_attn<<<BATCH * NH * 32, 256, 0, stream>>>(Qb, Kb, Vb, attb);
    k_proj<<<32 * 16, 256, 0, stream>>>(attb, wpt, bp, out);
}

// Round 6
// 219.830 us; speedup vs baseline: 1.2614x; 1.2614x over previous
//
#include <hip/hip_runtime.h>
#include <hip/hip_fp16.h>

#define BATCH 2
#define SEQ 2048
#define EMB 1024
#define NH 16
#define HDIM 64

typedef _Float16 h16;
typedef __attribute__((ext_vector_type(8))) _Float16 h8;
typedef __attribute__((ext_vector_type(4))) _Float16 h4;
typedef __attribute__((ext_vector_type(4))) float f32x4;

#define MFMA16(a, b, c) __builtin_amdgcn_mfma_f32_16x16x32_f16((a), (b), (c), 0, 0, 0)

// async global->LDS, 16B per lane. LDS dest is wave-uniform base + lane*16.
__device__ __forceinline__ void g2l16(const void* g, void* l) {
    __builtin_amdgcn_global_load_lds(
        (const __attribute__((address_space(1))) unsigned int*)g,
        (__attribute__((address_space(3))) unsigned int*)l, 16, 0, 0);
}

// ---------------------------------------------------------------------------
// x [B*S][E] f32 -> f16
__global__ __launch_bounds__(256) void k_cast_x(const float* __restrict__ x,
                                                h16* __restrict__ xh) {
    int i = (blockIdx.x * 256 + threadIdx.x) * 4;
    float4 v = *(const float4*)(x + i);
    h4 o = { (h16)v.x, (h16)v.y, (h16)v.z, (h16)v.w };
    *(h4*)(xh + i) = o;
}

// Wq/Wk/Wv [NH][EMB][HDIM] f32 -> wcat[(h*3+mat)*64+d][EMB] f16 (n-major, k-contig)
__global__ __launch_bounds__(256) void k_tr_qkv3(const float* __restrict__ wq,
                                                 const float* __restrict__ wk,
                                                 const float* __restrict__ wv,
                                                 h16* __restrict__ wcat) {
    int o = blockIdx.x * 256 + threadIdx.x;       // [0, 3M)
    int mat = o >> 20;
    int w = o & ((1 << 20) - 1);
    int e = w & 1023, d = (w >> 10) & 63, h = w >> 16;
    const float* src = (mat == 0) ? wq : (mat == 1) ? wk : wv;
    wcat[(((size_t)(h * 3 + mat) * 64 + d) << 10) | e] =
        (h16)src[((size_t)(h << 10) + e) * 64 + d];
}

// Wproj [PROJ_IN][EMB] f32 -> wpt [EMB_n][PROJ_IN_k] f16
__global__ __launch_bounds__(256) void k_tr_wp(const float* __restrict__ w,
                                               h16* __restrict__ wt) {
    int o = blockIdx.x * 256 + threadIdx.x;
    int k = o & 1023, n = o >> 10;
    wt[o] = (h16)w[((size_t)k << 10) | n];
}

// ---------------------------------------------------------------------------
// m97-structure QKV GEMM: M=4096, N=3072, K=1024. 128x128 tile, BK=32.
// Q outputs pre-scaled by 0.125*log2e (folds softmax scale into exp2 domain).
__global__ __launch_bounds__(256) void k_qkv(
    const h16* __restrict__ xh, const h16* __restrict__ wcat,
    h16* __restrict__ Q, h16* __restrict__ Kk, h16* __restrict__ Vt) {
    __shared__ h16 As[128 * 32];
    __shared__ h16 Bs[128 * 32];
    int tid = threadIdx.x;
    int wave = tid >> 6, lane = tid & 63;
    int lr = lane & 15, lg = lane >> 4;
    int wr = wave >> 1, wc = wave & 1;
    int swz = (blockIdx.x & 7) * 96 + (blockIdx.x >> 3);   // 768 = 8*96 bijective
    int nt = swz % 24, mt = swz / 24;

    const char* Ab = (const char*)xh + (size_t)mt * 128 * 2048;
    const char* Bb = (const char*)wcat + (size_t)nt * 128 * 2048;
    int srow = tid >> 2;
    int scolb = (((tid & 3) ^ (srow & 3))) * 16;
    const char* As0 = Ab + (size_t)srow * 2048 + scolb;
    const char* Bs0 = Bb + (size_t)srow * 2048 + scolb;
    h16* AsW = As + wave * 512;
    h16* BsW = Bs + wave * 512;

    f32x4 acc[4][4];
#pragma unroll
    for (int m = 0; m < 4; m++)
#pragma unroll
        for (int n = 0; n < 4; n++) acc[m][n] = (f32x4){0.f, 0.f, 0.f, 0.f};

    for (int k0 = 0; k0 < 1024; k0 += 32) {
        size_t kb = (size_t)k0 * 2;
        g2l16(As0 + kb, AsW);
        g2l16(As0 + 64 * 2048 + kb, AsW + 2048);
        g2l16(Bs0 + kb, BsW);
        g2l16(Bs0 + 64 * 2048 + kb, BsW + 2048);
        __syncthreads();
        h8 a[4], b[4];
#pragma unroll
        for (int m = 0; m < 4; m++)
            a[m] = *(const h8*)&As[(wr * 64 + m * 16 + lr) * 32 + (lg ^ (lr & 3)) * 8];
#pragma unroll
        for (int n = 0; n < 4; n++)
            b[n] = *(const h8*)&Bs[(wc * 64 + n * 16 + lr) * 32 + (lg ^ (lr & 3)) * 8];
#pragma unroll
        for (int m = 0; m < 4; m++)
#pragma unroll
            for (int n = 0; n < 4; n++)
                acc[m][n] = MFMA16(a[m], b[n], acc[m][n]);
        __syncthreads();
    }

    int g = nt * 2 + wc;
    int mat = g % 3, hh = g / 3;
    int row0 = mt * 128 + wr * 64;
    if (mat == 2) {
#pragma unroll
        for (int m = 0; m < 4; m++)
#pragma unroll
            for (int n = 0; n < 4; n++) {
                int row = row0 + m * 16 + lg * 4;
                int b = row >> 11, s = row & 2047;
                int bh = b * 16 + hh;
                int d = n * 16 + lr;
                h4 o = { (h16)acc[m][n][0], (h16)acc[m][n][1],
                         (h16)acc[m][n][2], (h16)acc[m][n][3] };
                *(h4*)&Vt[((size_t)bh * 64 + d) * 2048 + s] = o;
            }
    } else {
        h16* dst = mat ? Kk : Q;
        float qs = mat ? 1.0f : 0.18033688011112042f;   // 0.125*log2(e) for Q
#pragma unroll
        for (int m = 0; m < 4; m++)
#pragma unroll
            for (int n = 0; n < 4; n++)
#pragma unroll
                for (int r = 0; r < 4; r++) {
                    int row = row0 + m * 16 + lg * 4 + r;
                    int bh = (row >> 11) * 16 + hh, s = row & 2047;
                    dst[((size_t)bh * 2048 + s) * 64 + n * 16 + lr] =
                        (h16)(acc[m][n][r] * qs);
                }
    }
}

// ---------------------------------------------------------------------------
// m97-structure out-projection: M=4096, N=1024, K=1024. 128x64 tile, BK=32.
__global__ __launch_bounds__(256) void k_proj(
    const h16* __restrict__ att, const h16* __restrict__ wpt,
    const float* __restrict__ bias, float* __restrict__ out) {
    __shared__ h16 As[128 * 32];
    __shared__ h16 Bs[64 * 32];
    int tid = threadIdx.x;
    int wave = tid >> 6, lane = tid & 63;
    int lr = lane & 15, lg = lane >> 4;
    int swz = (blockIdx.x & 7) * 64 + (blockIdx.x >> 3);   // 512 = 8*64 bijective
    int nt = swz & 15, mt = swz >> 4;

    const char* Ab = (const char*)att + (size_t)mt * 128 * 2048;
    const char* Bb = (const char*)wpt + (size_t)nt * 64 * 2048;
    int srow = tid >> 2;
    int scolb = (((tid & 3) ^ (srow & 3))) * 16;
    const char* As0 = Ab + (size_t)srow * 2048 + scolb;
    const char* Bs0 = Bb + (size_t)srow * 2048 + scolb;
    h16* AsW = As + wave * 512;
    h16* BsW = Bs + wave * 512;

    f32x4 acc[2][4];
#pragma unroll
    for (int m = 0; m < 2; m++)
#pragma unroll
        for (int n = 0; n < 4; n++) acc[m][n] = (f32x4){0.f, 0.f, 0.f, 0.f};

    for (int k0 = 0; k0 < 1024; k0 += 32) {
        size_t kb = (size_t)k0 * 2;
        g2l16(As0 + kb, AsW);
        g2l16(As0 + 64 * 2048 + kb, AsW + 2048);
        g2l16(Bs0 + kb, BsW);
        __syncthreads();
        h8 a[2], b[4];
#pragma unroll
        for (int m = 0; m < 2; m++)
            a[m] = *(const h8*)&As[(wave * 32 + m * 16 + lr) * 32 + (lg ^ (lr & 3)) * 8];
#pragma unroll
        for (int n = 0; n < 4; n++)
            b[n] = *(const h8*)&Bs[(n * 16 + lr) * 32 + (lg ^ (lr & 3)) * 8];
#pragma unroll
        for (int m = 0; m < 2; m++)
#pragma unroll
            for (int n = 0; n < 4; n++)
                acc[m][n] = MFMA16(a[m], b[n], acc[m][n]);
        __syncthreads();
    }

#pragma unroll
    for (int m = 0; m < 2; m++)
#pragma unroll
        for (int n = 0; n < 4; n++)
#pragma unroll
            for (int r = 0; r < 4; r++) {
                int row = mt * 128 + wave * 32 + m * 16 + lg * 4 + r;
                int col = nt * 64 + n * 16 + lr;
                out[(size_t)row * 1024 + col] = acc[m][n][r] + bias[col];
            }
}

// ---------------------------------------------------------------------------
// LDS-staged transposed flash attention.
// Block = 4 waves x 32 q-rows = 128-row chunk. K/V 64-tiles double-buffered
// in LDS (global_load_lds w=16, XOR granule swizzle both sides), shared by
// all 4 waves. Raw s_barrier + counted vmcnt(4) (no full drains in-loop).
// Per-wave causal skip of fully-masked tiles. Q pre-scaled in k_qkv.
// Stage: wave stages its 16 K-rows + 16 V-rows (4 g2l16 calls).
__device__ __forceinline__ void stage_kv(h16* Kb, h16* Vb,
                                         const h16* Kp, const h16* Vp,
                                         int ks0, int wave, int lane) {
    int rl = lane >> 3, gc = lane & 7;
#pragma unroll
    for (int q = 0; q < 2; q++) {
        int br = wave * 16 + q * 8;
        int row = br + rl;
        int sg = gc ^ (row & 7);
        // K [s][64]: row stride 128B, contiguous
        g2l16((const char*)Kp + ((size_t)(ks0 + row) << 7) + (sg << 4), Kb + br * 64);
        // V^T [d][2048]: row stride 4096B, 128B slice at col ks0
        g2l16((const char*)Vp + ((size_t)row << 12) + (ks0 << 1) + (sg << 4), Vb + br * 64);
    }
}

__global__ __launch_bounds__(256) void k_attn(
    const h16* __restrict__ Q, const h16* __restrict__ Kk,
    const h16* __restrict__ Vt, h16* __restrict__ att) {
    __shared__ h16 Kb[2][64 * 64];   // 16 KB
    __shared__ h16 Vb[2][64 * 64];   // 16 KB
    __shared__ h16 lp[4][32][72];    // 18 KB, per-wave P tile

    // locality+balance swizzle: XCD x sees only bh % 8 == x (2MB K/V -> L2);
    // CU block-pairs (i, i+256) get complementary causal lengths g, 15-g.
    int i = blockIdx.x;
    int x = i & 7, rest = i >> 3;
    int bh = x + ((rest & 3) << 3);
    int gslot = rest >> 2;
    int g = (gslot < 8) ? gslot : (15 - (gslot - 8));
    int b = bh >> 4, h = bh & 15;
    int wave = threadIdx.x >> 6, lane = threadIdx.x & 63;
    int lr = lane & 15, lg = lane >> 4;
    int lx = lr & 7;
    int q0w = g * 128 + wave * 32;

    const h16* Qp = Q + (size_t)bh * SEQ * HDIM;
    const h16* Kp = Kk + (size_t)bh * SEQ * HDIM;
    const h16* Vp = Vt + (size_t)bh * HDIM * SEQ;

    // Q as B-operand (col=q, k-dim=d); already scaled by 0.125*log2e
    h8 qb[2][2];
#pragma unroll
    for (int qf = 0; qf < 2; qf++)
#pragma unroll
        for (int dc = 0; dc < 2; dc++)
            qb[qf][dc] = *(const h8*)(Qp + (size_t)(q0w + qf * 16 + lr) * 64 + dc * 32 + lg * 8);

    stage_kv(Kb[0], Vb[0], Kp, Vp, 0, wave, lane);

    float mx[2] = {0.f, 0.f}, lsum[2] = {0.f, 0.f};
    f32x4 ot[4][2];
#pragma unroll
    for (int df = 0; df < 4; df++)
#pragma unroll
        for (int qf = 0; qf < 2; qf++) ot[df][qf] = (f32x4){0.f, 0.f, 0.f, 0.f};

    int nkt = 2 * g + 2;
    for (int kt = 0; kt < nkt; ++kt) {
        int ks0 = kt << 6;
        int cur = kt & 1;
        if (kt + 1 < nkt) {
            stage_kv(Kb[cur ^ 1], Vb[cur ^ 1], Kp, Vp, (kt + 1) << 6, wave, lane);
            asm volatile("s_waitcnt vmcnt(4)" ::: "memory");   // tile kt ready; next 4 in flight
        } else {
            asm volatile("s_waitcnt vmcnt(0)" ::: "memory");
        }
        __builtin_amdgcn_s_barrier();
        __builtin_amdgcn_sched_barrier(0);
        if (ks0 <= q0w + 31) {   // wave-uniform causal skip
            const h16* Kc = Kb[cur];
            const h16* Vc = Vb[cur];
            // ---- S^T = K @ Q^T : rows=k (4 frags), cols=q (2 frags)
            f32x4 st[4][2];
#pragma unroll
            for (int kf = 0; kf < 4; kf++)
#pragma unroll
                for (int qf = 0; qf < 2; qf++) st[kf][qf] = (f32x4){0.f, 0.f, 0.f, 0.f};
#pragma unroll
            for (int dc = 0; dc < 2; dc++) {
                h8 ka[4];
#pragma unroll
                for (int kf = 0; kf < 4; kf++)
                    ka[kf] = *(const h8*)&Kc[(kf * 16 + lr) * 64 + (((dc * 4 + lg) ^ lx) << 3)];
#pragma unroll
                for (int kf = 0; kf < 4; kf++)
#pragma unroll
                    for (int qf = 0; qf < 2; qf++)
                        st[kf][qf] = MFMA16(ka[kf], qb[qf][dc], st[kf][qf]);
            }
            // ---- V frags from LDS
            h8 va[2][4];
#pragma unroll
            for (int kc = 0; kc < 2; kc++)
#pragma unroll
                for (int df = 0; df < 4; df++)
                    va[kc][df] = *(const h8*)&Vc[(df * 16 + lr) * 64 + (((kc * 4 + lg) ^ lx) << 3)];
            // ---- causal mask (boundary tiles only; wave-uniform branch)
            if (ks0 + 64 > q0w) {
#pragma unroll
                for (int kf = 0; kf < 4; kf++)
#pragma unroll
                    for (int qf = 0; qf < 2; qf++) {
                        int qg = q0w + qf * 16 + lr;
#pragma unroll
                        for (int r = 0; r < 4; r++) {
                            int kg = ks0 + kf * 16 + lg * 4 + r;
                            if (kg > qg) st[kf][qf][r] = -1e30f;
                        }
                    }
            }
            // ---- per-q tile max: 15 in-lane fmax + 2 shfls
            float tm[2];
#pragma unroll
            for (int qf = 0; qf < 2; qf++) {
                float t = st[0][qf][0];
#pragma unroll
                for (int kf = 0; kf < 4; kf++)
#pragma unroll
                    for (int r = 0; r < 4; r++) t = fmaxf(t, st[kf][qf][r]);
                t = fmaxf(t, __shfl_xor(t, 16));
                t = fmaxf(t, __shfl_xor(t, 32));
                tm[qf] = t;
            }
            // ---- defer-max: rescale only if tile max grew past THR=8
            if (__any((tm[0] > mx[0] + 8.f) || (tm[1] > mx[1] + 8.f))) {
#pragma unroll
                for (int qf = 0; qf < 2; qf++) {
                    float mn = fmaxf(mx[qf], tm[qf]);
                    float corr = exp2f(mx[qf] - mn);
                    lsum[qf] *= corr;
#pragma unroll
                    for (int df = 0; df < 4; df++) ot[df][qf] *= corr;
                    mx[qf] = mn;
                }
            }
            // ---- P = exp2(st - m), packed b64 LDS write
            float ts[2] = {0.f, 0.f};
#pragma unroll
            for (int kf = 0; kf < 4; kf++)
#pragma unroll
                for (int qf = 0; qf < 2; qf++) {
                    float p0 = exp2f(st[kf][qf][0] - mx[qf]);
                    float p1 = exp2f(st[kf][qf][1] - mx[qf]);
                    float p2 = exp2f(st[kf][qf][2] - mx[qf]);
                    float p3 = exp2f(st[kf][qf][3] - mx[qf]);
                    ts[qf] += (p0 + p1) + (p2 + p3);
                    h4 ph = { (h16)p0, (h16)p1, (h16)p2, (h16)p3 };
                    *(h4*)&lp[wave][qf * 16 + lr][kf * 16 + lg * 4] = ph;
                }
#pragma unroll
            for (int qf = 0; qf < 2; qf++) {
                float t = ts[qf];
                t += __shfl_xor(t, 16);
                t += __shfl_xor(t, 32);
                lsum[qf] += t;
            }
            // ---- O^T += V^T @ P^T
#pragma unroll
            for (int kc = 0; kc < 2; kc++) {
                h8 pb[2];
#pragma unroll
                for (int qf = 0; qf < 2; qf++)
                    pb[qf] = *(const h8*)&lp[wave][qf * 16 + lr][kc * 32 + lg * 8];
#pragma unroll
                for (int df = 0; df < 4; df++)
#pragma unroll
                    for (int qf = 0; qf < 2; qf++)
                        ot[df][qf] = MFMA16(va[kc][df], pb[qf], ot[df][qf]);
            }
        }
        __builtin_amdgcn_s_barrier();
    }
    // ---- epilogue: O^T/l -> att[b*S+q][h*64+d], 4 consecutive d packed
#pragma unroll
    for (int qf = 0; qf < 2; qf++) {
        float rl = 1.f / lsum[qf];
        int q = q0w + qf * 16 + lr;
#pragma unroll
        for (int df = 0; df < 4; df++) {
            h4 o = { (h16)(ot[df][qf][0] * rl), (h16)(ot[df][qf][1] * rl),
                     (h16)(ot[df][qf][2] * rl), (h16)(ot[df][qf][3] * rl) };
            *(h4*)&att[((size_t)(b * SEQ + q)) * 1024 + h * 64 + df * 16 + lg * 4] = o;
        }
    }
}

// ---------------------------------------------------------------------------
extern "C" void kernel_launch(void* const* d_in, const int* in_sizes, int n_in,
                              void* d_out, int out_size, void* d_ws, size_t ws_size,
                              hipStream_t stream) {
    const float* x = (const float*)d_in[0];
    const float* Wq = (const float*)d_in[1];
    const float* Wk = (const float*)d_in[2];
    const float* Wv = (const float*)d_in[3];
    const float* Wp = (const float*)d_in[4];
    const float* bp = (const float*)d_in[5];
    float* out = (float*)d_out;

    char* p = (char*)d_ws;
    h16* xh = (h16*)p;   p += (size_t)BATCH * SEQ * EMB * 2;
    h16* wcat = (h16*)p; p += (size_t)NH * 3 * HDIM * EMB * 2;
    h16* wpt = (h16*)p;  p += (size_t)EMB * EMB * 2;
    h16* Qb = (h16*)p;   p += (size_t)BATCH * NH * SEQ * HDIM * 2;
    h16* Kb = (h16*)p;   p += (size_t)BATCH * NH * SEQ * HDIM * 2;
    h16* Vb = (h16*)p;   p += (size_t)BATCH * NH * SEQ * HDIM * 2;
    h16* attb = (h16*)p;

    k_cast_x<<<(BATCH * SEQ * EMB) / 4 / 256, 256, 0, stream>>>(x, xh);
    k_tr_qkv3<<<3 * NH * EMB * HDIM / 256, 256, 0, stream>>>(Wq, Wk, Wv, wcat);
    k_tr_wp<<<EMB * EMB / 256, 256, 0, stream>>>(Wp, wpt);
    k_qkv<<<32 * 24, 256, 0, stream>>>(xh, wcat, Qb, Kb, Vb);
    k_attn<<<512, 256, 0, stream>>>(Qb, Kb, Vb, attb);
    k_proj<<<32 * 16, 256, 0, stream>>>(attb, wpt, bp, out);
}

// Round 7
// 184.726 us; speedup vs baseline: 1.5011x; 1.1900x over previous
//
#include <hip/hip_runtime.h>
#include <hip/hip_fp16.h>

#define BATCH 2
#define SEQ 2048
#define EMB 1024
#define NH 16
#define HDIM 64

typedef _Float16 h16;
typedef __attribute__((ext_vector_type(8))) _Float16 h8;
typedef __attribute__((ext_vector_type(4))) _Float16 h4;
typedef __attribute__((ext_vector_type(2))) _Float16 h2;
typedef __attribute__((ext_vector_type(4))) float f32x4;

#define MFMA16(a, b, c) __builtin_amdgcn_mfma_f32_16x16x32_f16((a), (b), (c), 0, 0, 0)

// async global->LDS, 16B per lane. LDS dest is wave-uniform base + lane*16.
__device__ __forceinline__ void g2l16(const void* g, void* l) {
    __builtin_amdgcn_global_load_lds(
        (const __attribute__((address_space(1))) unsigned int*)g,
        (__attribute__((address_space(3))) unsigned int*)l, 16, 0, 0);
}

// ---------------------------------------------------------------------------
// x [B*S][E] f32 -> f16
__global__ __launch_bounds__(256) void k_cast_x(const float* __restrict__ x,
                                                h16* __restrict__ xh) {
    int i = (blockIdx.x * 256 + threadIdx.x) * 4;
    float4 v = *(const float4*)(x + i);
    h4 o = { (h16)v.x, (h16)v.y, (h16)v.z, (h16)v.w };
    *(h4*)(xh + i) = o;
}

// Wq/Wk/Wv [NH][EMB][HDIM] f32 -> wcat[(h*3+mat)*64+d][EMB] f16.
// Coalesced both sides via 64x64 LDS tile (padded stride 65).
__global__ __launch_bounds__(256) void k_tr_qkv3(const float* __restrict__ wq,
                                                 const float* __restrict__ wk,
                                                 const float* __restrict__ wv,
                                                 h16* __restrict__ wcat) {
    __shared__ h16 ld[64][65];
    int g = blockIdx.x >> 4;              // output row-group 0..47
    int t = blockIdx.x & 15;              // e-tile
    int h = g / 3, mat = g - h * 3;
    const float* src = (mat == 0) ? wq : (mat == 1) ? wk : wv;
    int e0 = t * 64;
    int c0 = threadIdx.x & 63, r0 = threadIdx.x >> 6;
#pragma unroll
    for (int i = 0; i < 16; i++) {
        int e = i * 4 + r0;               // read coalesced over d (256B rows)
        ld[c0][e] = (h16)src[((size_t)((h << 10) | (e0 + e))) * 64 + c0];
    }
    __syncthreads();
#pragma unroll
    for (int i = 0; i < 16; i++) {
        int d = i * 4 + r0;               // write coalesced over e (128B rows)
        wcat[((size_t)(g * 64 + d) << 10) | (e0 + c0)] = ld[d][c0];
    }
}

// Wproj [PROJ_IN][EMB] f32 -> wpt [EMB_n][PROJ_IN_k] f16, same LDS-tile scheme.
__global__ __launch_bounds__(256) void k_tr_wp(const float* __restrict__ w,
                                               h16* __restrict__ wt) {
    __shared__ h16 ld[64][65];
    int kt = blockIdx.x & 15, ntl = blockIdx.x >> 4;
    int c0 = threadIdx.x & 63, r0 = threadIdx.x >> 6;
#pragma unroll
    for (int i = 0; i < 16; i++) {
        int k = i * 4 + r0;               // read coalesced over n
        ld[c0][k] = (h16)w[((size_t)(kt * 64 + k) << 10) | (ntl * 64 + c0)];
    }
    __syncthreads();
#pragma unroll
    for (int i = 0; i < 16; i++) {
        int n = i * 4 + r0;               // write coalesced over k
        wt[((size_t)(ntl * 64 + n) << 10) | (kt * 64 + c0)] = ld[n][c0];
    }
}

// ---------------------------------------------------------------------------
// QKV GEMM: M=4096, N=3072, K=1024. 128x128 tile, BK=64 (16 K-steps, half the
// barriers of BK=32). LDS 32KB. Q pre-scaled by 0.125*log2e.
__global__ __launch_bounds__(256) void k_qkv(
    const h16* __restrict__ xh, const h16* __restrict__ wcat,
    h16* __restrict__ Q, h16* __restrict__ Kk, h16* __restrict__ Vt) {
    __shared__ h16 As[128 * 64];   // 16KB
    __shared__ h16 Bs[128 * 64];   // 16KB
    int tid = threadIdx.x;
    int wave = tid >> 6, lane = tid & 63;
    int lr = lane & 15, lg = lane >> 4, lx = lr & 7;
    int wr = wave >> 1, wc = wave & 1;
    int swz = (blockIdx.x & 7) * 96 + (blockIdx.x >> 3);   // 768 = 8*96 bijective
    int nt = swz % 24, mt = swz / 24;

    const char* Ab = (const char*)xh + (size_t)mt * 128 * 2048;
    const char* Bb = (const char*)wcat + (size_t)nt * 128 * 2048;
    int rl = lane >> 3, gc = lane & 7;
    size_t lofs = (size_t)rl * 2048 + ((gc ^ rl) << 4);    // per-lane const src offset

    f32x4 acc[4][4];
#pragma unroll
    for (int m = 0; m < 4; m++)
#pragma unroll
        for (int n = 0; n < 4; n++) acc[m][n] = (f32x4){0.f, 0.f, 0.f, 0.f};

    for (int k0 = 0; k0 < 1024; k0 += 64) {
        size_t kb = (size_t)k0 * 2;
#pragma unroll
        for (int c = 0; c < 4; c++) {
            int rb = c * 32 + wave * 8;
            g2l16(Ab + (size_t)rb * 2048 + lofs + kb, As + rb * 64);
            g2l16(Bb + (size_t)rb * 2048 + lofs + kb, Bs + rb * 64);
        }
        __syncthreads();
#pragma unroll
        for (int dc = 0; dc < 2; dc++) {
            h8 a[4], b[4];
#pragma unroll
            for (int m = 0; m < 4; m++)
                a[m] = *(const h8*)&As[(wr * 64 + m * 16 + lr) * 64 + (((dc * 4 + lg) ^ lx) << 3)];
#pragma unroll
            for (int n = 0; n < 4; n++)
                b[n] = *(const h8*)&Bs[(wc * 64 + n * 16 + lr) * 64 + (((dc * 4 + lg) ^ lx) << 3)];
#pragma unroll
            for (int m = 0; m < 4; m++)
#pragma unroll
                for (int n = 0; n < 4; n++)
                    acc[m][n] = MFMA16(a[m], b[n], acc[m][n]);
        }
        __syncthreads();
    }

    int g = nt * 2 + wc;
    int mat = g % 3, hh = g / 3;
    int row0 = mt * 128 + wr * 64;
    if (mat == 2) {
#pragma unroll
        for (int m = 0; m < 4; m++)
#pragma unroll
            for (int n = 0; n < 4; n++) {
                int row = row0 + m * 16 + lg * 4;
                int b = row >> 11, s = row & 2047;
                int bh = b * 16 + hh;
                int d = n * 16 + lr;
                h4 o = { (h16)acc[m][n][0], (h16)acc[m][n][1],
                         (h16)acc[m][n][2], (h16)acc[m][n][3] };
                *(h4*)&Vt[((size_t)bh * 64 + d) * 2048 + s] = o;
            }
    } else {
        h16* dst = mat ? Kk : Q;
        float qs = mat ? 1.0f : 0.18033688011112042f;   // 0.125*log2(e) for Q
#pragma unroll
        for (int m = 0; m < 4; m++)
#pragma unroll
            for (int n = 0; n < 4; n++)
#pragma unroll
                for (int r = 0; r < 4; r++) {
                    int row = row0 + m * 16 + lg * 4 + r;
                    int bh = (row >> 11) * 16 + hh, s = row & 2047;
                    dst[((size_t)bh * 2048 + s) * 64 + n * 16 + lr] =
                        (h16)(acc[m][n][r] * qs);
                }
    }
}

// ---------------------------------------------------------------------------
// Out-projection: M=4096, N=1024, K=1024. 128x64 tile, BK=64. LDS 24KB.
__global__ __launch_bounds__(256) void k_proj(
    const h16* __restrict__ att, const h16* __restrict__ wpt,
    const float* __restrict__ bias, float* __restrict__ out) {
    __shared__ h16 As[128 * 64];   // 16KB
    __shared__ h16 Bs[64 * 64];    // 8KB
    int tid = threadIdx.x;
    int wave = tid >> 6, lane = tid & 63;
    int lr = lane & 15, lg = lane >> 4, lx = lr & 7;
    int swz = (blockIdx.x & 7) * 64 + (blockIdx.x >> 3);   // 512 = 8*64 bijective
    int nt = swz & 15, mt = swz >> 4;

    const char* Ab = (const char*)att + (size_t)mt * 128 * 2048;
    const char* Bb = (const char*)wpt + (size_t)nt * 64 * 2048;
    int rl = lane >> 3, gc = lane & 7;
    size_t lofs = (size_t)rl * 2048 + ((gc ^ rl) << 4);

    f32x4 acc[2][4];
#pragma unroll
    for (int m = 0; m < 2; m++)
#pragma unroll
        for (int n = 0; n < 4; n++) acc[m][n] = (f32x4){0.f, 0.f, 0.f, 0.f};

    for (int k0 = 0; k0 < 1024; k0 += 64) {
        size_t kb = (size_t)k0 * 2;
#pragma unroll
        for (int c = 0; c < 4; c++) {
            int rb = c * 32 + wave * 8;
            g2l16(Ab + (size_t)rb * 2048 + lofs + kb, As + rb * 64);
            if (c < 2)
                g2l16(Bb + (size_t)rb * 2048 + lofs + kb, Bs + rb * 64);
        }
        __syncthreads();
#pragma unroll
        for (int dc = 0; dc < 2; dc++) {
            h8 a[2], b[4];
#pragma unroll
            for (int m = 0; m < 2; m++)
                a[m] = *(const h8*)&As[(wave * 32 + m * 16 + lr) * 64 + (((dc * 4 + lg) ^ lx) << 3)];
#pragma unroll
            for (int n = 0; n < 4; n++)
                b[n] = *(const h8*)&Bs[(n * 16 + lr) * 64 + (((dc * 4 + lg) ^ lx) << 3)];
#pragma unroll
            for (int m = 0; m < 2; m++)
#pragma unroll
                for (int n = 0; n < 4; n++)
                    acc[m][n] = MFMA16(a[m], b[n], acc[m][n]);
        }
        __syncthreads();
    }

#pragma unroll
    for (int m = 0; m < 2; m++)
#pragma unroll
        for (int n = 0; n < 4; n++)
#pragma unroll
            for (int r = 0; r < 4; r++) {
                int row = mt * 128 + wave * 32 + m * 16 + lg * 4 + r;
                int col = nt * 64 + n * 16 + lr;
                out[(size_t)row * 1024 + col] = acc[m][n][r] + bias[col];
            }
}

// ---------------------------------------------------------------------------
// LDS-staged transposed flash attention, 64-row q-chunks.
// Block = 4 waves x 16 q-rows; grid 1024 -> 4 blocks/CU (LDS exactly 40KB),
// 16 waves/CU. K/V 64-tiles double-buffered (global_load_lds + XOR granule
// swizzle); every wave computes every tile (no divergent skip); mask only on
// the block-uniform last tile. P via XOR-swizzled 8KB LDS tile.
// Per-CU block set {c, c+8, 31-c, 23-c} = constant 66 tiles.
__device__ __forceinline__ void stage_kv(h16* Kb, h16* Vb,
                                         const h16* Kp, const h16* Vp,
                                         int ks0, int wave, int lane) {
    int rl = lane >> 3, gc = lane & 7;
    int sg = gc ^ rl;
#pragma unroll
    for (int c8 = 0; c8 < 2; c8++) {
        int rb = wave * 16 + c8 * 8;
        int row = rb + rl;
        // K [s][64]: row stride 128B
        g2l16((const char*)Kp + ((size_t)(ks0 + row) << 7) + (sg << 4), Kb + rb * 64);
        // V^T [d][2048]: row stride 4096B, 128B slice at col ks0
        g2l16((const char*)Vp + ((size_t)row << 12) + ((size_t)ks0 << 1) + (sg << 4), Vb + rb * 64);
    }
}

__global__ __launch_bounds__(256, 4) void k_attn(
    const h16* __restrict__ Q, const h16* __restrict__ Kk,
    const h16* __restrict__ Vt, h16* __restrict__ att) {
    __shared__ h16 Kb[2][64 * 64];   // 16 KB
    __shared__ h16 Vb[2][64 * 64];   // 16 KB
    __shared__ h16 lp[4][16][64];    // 8 KB, XOR-swizzled per-wave P tile

    // XCD locality (bh % 8 == XCD id -> 2MB K/V per XCD L2) + causal balance.
    int i = blockIdx.x;
    int x = i & 7, rest = i >> 3;
    int bh = x + ((rest & 3) << 3);
    int cslot = rest >> 2;                     // 0..31
    int c = (cslot < 16) ? cslot : 47 - cslot; // bijective, pairs c <-> 31-c
    int b = bh >> 4, h = bh & 15;
    int wave = threadIdx.x >> 6, lane = threadIdx.x & 63;
    int lr = lane & 15, lg = lane >> 4, lx = lr & 7;
    int q0w = c * 64 + wave * 16;

    const h16* Qp = Q + (size_t)bh * SEQ * HDIM;
    const h16* Kp = Kk + (size_t)bh * SEQ * HDIM;
    const h16* Vp = Vt + (size_t)bh * HDIM * SEQ;

    // Q as B-operand (col=q, k-dim=d); already scaled by 0.125*log2e
    h8 qb[2];
#pragma unroll
    for (int dc = 0; dc < 2; dc++)
        qb[dc] = *(const h8*)(Qp + (size_t)(q0w + lr) * 64 + dc * 32 + lg * 8);

    stage_kv(Kb[0], Vb[0], Kp, Vp, 0, wave, lane);

    float mx = 0.f, lsum = 0.f;
    f32x4 ot[4];
#pragma unroll
    for (int df = 0; df < 4; df++) ot[df] = (f32x4){0.f, 0.f, 0.f, 0.f};

    int nkt = c + 1;   // all 4 waves need tiles 0..c (wave*16+15 < 64)
    for (int kt = 0; kt < nkt; ++kt) {
        int ks0 = kt << 6;
        int cur = kt & 1;
        if (kt + 1 < nkt) {
            stage_kv(Kb[cur ^ 1], Vb[cur ^ 1], Kp, Vp, (kt + 1) << 6, wave, lane);
            asm volatile("s_waitcnt vmcnt(4)" ::: "memory");
        } else {
            asm volatile("s_waitcnt vmcnt(0)" ::: "memory");
        }
        __builtin_amdgcn_s_barrier();
        __builtin_amdgcn_sched_barrier(0);
        const h16* Kc = Kb[cur];
        const h16* Vc = Vb[cur];
        // ---- S^T = K @ Q^T : rows=k (4 frags), col=q (1 frag)
        f32x4 st[4];
#pragma unroll
        for (int kf = 0; kf < 4; kf++) st[kf] = (f32x4){0.f, 0.f, 0.f, 0.f};
#pragma unroll
        for (int dc = 0; dc < 2; dc++) {
            h8 ka[4];
#pragma unroll
            for (int kf = 0; kf < 4; kf++)
                ka[kf] = *(const h8*)&Kc[(kf * 16 + lr) * 64 + (((dc * 4 + lg) ^ lx) << 3)];
#pragma unroll
            for (int kf = 0; kf < 4; kf++)
                st[kf] = MFMA16(ka[kf], qb[dc], st[kf]);
        }
        // ---- V frags from LDS (independent: scheduler can hoist past softmax)
        h8 va[2][4];
#pragma unroll
        for (int kc = 0; kc < 2; kc++)
#pragma unroll
            for (int df = 0; df < 4; df++)
                va[kc][df] = *(const h8*)&Vc[(df * 16 + lr) * 64 + (((kc * 4 + lg) ^ lx) << 3)];
        // ---- causal mask: block-uniform, last tile only
        if (kt == nkt - 1) {
            int qg = q0w + lr;
#pragma unroll
            for (int kf = 0; kf < 4; kf++)
#pragma unroll
                for (int r = 0; r < 4; r++) {
                    int kg = ks0 + kf * 16 + lg * 4 + r;
                    if (kg > qg) st[kf][r] = -1e30f;
                }
        }
        // ---- per-q tile max: 15 in-lane fmax + 2 shfls
        float tm = st[0][0];
#pragma unroll
        for (int kf = 0; kf < 4; kf++)
#pragma unroll
            for (int r = 0; r < 4; r++) tm = fmaxf(tm, st[kf][r]);
        tm = fmaxf(tm, __shfl_xor(tm, 16));
        tm = fmaxf(tm, __shfl_xor(tm, 32));
        // ---- defer-max: rescale only if tile max grew past THR=8
        if (__any(tm > mx + 8.f)) {
            float mn = fmaxf(mx, tm);
            float corr = exp2f(mx - mn);
            lsum *= corr;
#pragma unroll
            for (int df = 0; df < 4; df++) ot[df] *= corr;
            mx = mn;
        }
        // ---- P = exp2(st - m), h4 packs -> XOR-swizzled LDS
        float ts = 0.f;
#pragma unroll
        for (int kf = 0; kf < 4; kf++) {
            float p0 = exp2f(st[kf][0] - mx);
            float p1 = exp2f(st[kf][1] - mx);
            float p2 = exp2f(st[kf][2] - mx);
            float p3 = exp2f(st[kf][3] - mx);
            ts += (p0 + p1) + (p2 + p3);
            h4 ph = { (h16)p0, (h16)p1, (h16)p2, (h16)p3 };
            *(h4*)&lp[wave][lr][(((kf * 2 + (lg >> 1)) ^ lx) << 3) + ((lg & 1) << 2)] = ph;
        }
        ts += __shfl_xor(ts, 16);
        ts += __shfl_xor(ts, 32);
        lsum += ts;
        // ---- O^T += V^T @ P^T
#pragma unroll
        for (int kc = 0; kc < 2; kc++) {
            h8 pb = *(const h8*)&lp[wave][lr][(((kc * 4 + lg) ^ lx) << 3)];
#pragma unroll
            for (int df = 0; df < 4; df++)
                ot[df] = MFMA16(va[kc][df], pb, ot[df]);
        }
        __builtin_amdgcn_s_barrier();
    }
    // ---- epilogue: O^T/l -> att[b*S+q][h*64+d]
    float rl2 = 1.f / lsum;
    int q = q0w + lr;
#pragma unroll
    for (int df = 0; df < 4; df++) {
        h4 o = { (h16)(ot[df][0] * rl2), (h16)(ot[df][1] * rl2),
                 (h16)(ot[df][2] * rl2), (h16)(ot[df][3] * rl2) };
        *(h4*)&att[((size_t)(b * SEQ + q)) * 1024 + h * 64 + df * 16 + lg * 4] = o;
    }
}

// ---------------------------------------------------------------------------
extern "C" void kernel_launch(void* const* d_in, const int* in_sizes, int n_in,
                              void* d_out, int out_size, void* d_ws, size_t ws_size,
                              hipStream_t stream) {
    const float* x = (const float*)d_in[0];
    const float* Wq = (const float*)d_in[1];
    const float* Wk = (const float*)d_in[2];
    const float* Wv = (const float*)d_in[3];
    const float* Wp = (const float*)d_in[4];
    const float* bp = (const float*)d_in[5];
    float* out = (float*)d_out;

    char* p = (char*)d_ws;
    h16* xh = (h16*)p;   p += (size_t)BATCH * SEQ * EMB * 2;
    h16* wcat = (h16*)p; p += (size_t)NH * 3 * HDIM * EMB * 2;
    h16* wpt = (h16*)p;  p += (size_t)EMB * EMB * 2;
    h16* Qb = (h16*)p;   p += (size_t)BATCH * NH * SEQ * HDIM * 2;
    h16* Kb = (h16*)p;   p += (size_t)BATCH * NH * SEQ * HDIM * 2;
    h16* Vb = (h16*)p;   p += (size_t)BATCH * NH * SEQ * HDIM * 2;
    h16* attb = (h16*)p;

    k_cast_x<<<(BATCH * SEQ * EMB) / 4 / 256, 256, 0, stream>>>(x, xh);
    k_tr_qkv3<<<48 * 16, 256, 0, stream>>>(Wq, Wk, Wv, wcat);
    k_tr_wp<<<16 * 16, 256, 0, stream>>>(Wp, wpt);
    k_qkv<<<32 * 24, 256, 0, stream>>>(xh, wcat, Qb, Kb, Vb);
    k_attn<<<1024, 256, 0, stream>>>(Qb, Kb, Vb, attb);
    k_proj<<<32 * 16, 256, 0, stream>>>(attb, wpt, bp, out);
}